// Round 1
// baseline (623.888 us; speedup 1.0000x reference)
//
#include <hip/hip_runtime.h>
#include <hip/hip_bf16.h>

#define NB 2
#define L 256
#define H 8
#define D 64
#define E 512
#define NL (NB * L)
#define RSQRT2 0.70710678118654752f

// ---------------- K0: transpose Wout [E][E] -> WoutT [c][e] ----------------
__global__ __launch_bounds__(256) void k0_transpose(const float* __restrict__ Wout,
                                                    float* __restrict__ WoutT) {
    __shared__ float tile[64][65];
    int t = threadIdx.x;
    int bi = blockIdx.x >> 3;   // e-tile
    int bj = blockIdx.x & 7;    // c-tile
    int tx = t & 63, ty = t >> 6;  // ty 0..3
#pragma unroll
    for (int m = 0; m < 16; m++) {
        int el = ty + (m << 2);
        tile[el][tx] = Wout[(size_t)(bi * 64 + el) * E + bj * 64 + tx];
    }
    __syncthreads();
#pragma unroll
    for (int m = 0; m < 16; m++) {
        int cl = ty + (m << 2);
        WoutT[(size_t)(bj * 64 + cl) * E + bi * 64 + tx] = tile[tx][cl];
    }
}

// ---------------- K1: per-(n,l) projections ----------------
__device__ __forceinline__ float dot64(const float* __restrict__ a,
                                       const float* __restrict__ w) {
    const float4* a4 = (const float4*)a;
    const float4* w4 = (const float4*)w;
    float acc = 0.f;
#pragma unroll
    for (int j = 0; j < 16; j++) {
        float4 x = a4[j], y = w4[j];
        acc = fmaf(x.x, y.x, acc);
        acc = fmaf(x.y, y.y, acc);
        acc = fmaf(x.z, y.z, acc);
        acc = fmaf(x.w, y.w, acc);
    }
    return acc;
}

__global__ __launch_bounds__(256) void k1_proj(
    const float* __restrict__ values, const float* __restrict__ keys,
    const float* __restrict__ query, const float* __restrict__ pos,
    const float* __restrict__ Wv, const float* __restrict__ Wk,
    const float* __restrict__ Wq, const float* __restrict__ Wpq,
    const float* __restrict__ Wpk, const float* __restrict__ Wrk,
    const float* __restrict__ Wrq,
    float* __restrict__ qv_ws, float* __restrict__ kv_ws,
    float* __restrict__ vv_ws, float* __restrict__ pq_ws,
    float* __restrict__ pk_ws, float* __restrict__ qrk_ws,
    float* __restrict__ krq_ws) {
    __shared__ float xq[E], xk[E], xv[E], xp[E];
    __shared__ float qs[E], ks[E];
    int t = threadIdx.x;
    int nl = blockIdx.x;
    size_t base = (size_t)nl * E;
    for (int j = t; j < E; j += 256) {
        xq[j] = query[base + j];
        xk[j] = keys[base + j];
        xv[j] = values[base + j];
        xp[j] = pos[base + j];
    }
    __syncthreads();
    // stage 1: y[h*64+i] = sum_j x[h*64+j] * W[i*64+j]
#pragma unroll
    for (int cc = 0; cc < 2; cc++) {
        int c = t + cc * 256;
        int h = c >> 6, i = c & 63;
        const float* xqh = xq + (h << 6);
        const float* xkh = xk + (h << 6);
        const float* xvh = xv + (h << 6);
        const float* xph = xp + (h << 6);
        float q_c = dot64(xqh, Wq + (i << 6));
        float k_c = dot64(xkh, Wk + (i << 6));
        float v_c = dot64(xvh, Wv + (i << 6));
        float pq_c = dot64(xph, Wpq + (i << 6));
        float pk_c = dot64(xph, Wpk + (i << 6));
        qv_ws[base + c] = q_c;
        kv_ws[base + c] = k_c;
        vv_ws[base + c] = v_c;
        pq_ws[base + c] = pq_c;
        pk_ws[base + c] = pk_c;
        qs[c] = q_c;
        ks[c] = k_c;
    }
    __syncthreads();
    // stage 2: qrk[h*64+d] = sum_i qs[h*64+i] * Wrk[i*64+d]; same for krq/Wrq
#pragma unroll
    for (int cc = 0; cc < 2; cc++) {
        int c = t + cc * 256;
        int h = c >> 6, d = c & 63;
        float aq = 0.f, ak = 0.f;
        const float* qh = qs + (h << 6);
        const float* kh = ks + (h << 6);
#pragma unroll 8
        for (int i = 0; i < 64; i++) {
            aq = fmaf(qh[i], Wrk[(i << 6) + d], aq);
            ak = fmaf(kh[i], Wrq[(i << 6) + d], ak);
        }
        qrk_ws[base + c] = aq;
        krq_ws[base + c] = ak;
    }
}

// ---------------- K2: main attention, one block per (n,q) ----------------
__global__ __launch_bounds__(256) void k2_attn(
    const float* __restrict__ rel, const float* __restrict__ mask,
    const float* __restrict__ qv_ws, const float* __restrict__ kv_ws,
    const float* __restrict__ vv_ws, const float* __restrict__ pq_ws,
    const float* __restrict__ pk_ws, const float* __restrict__ qrk_ws,
    const float* __restrict__ krq_ws, float* __restrict__ attn_ws) {
    __shared__ float e_s[H][L];   // energy -> exp(p)
    __shared__ float inv_s[H];
    int t = threadIdx.x;
    int b = blockIdx.x;          // b = n*L + q
    int n = b >> 8;
    size_t nq = (size_t)b;

    int lane128 = t & 127;
    int rowsel = t >> 7;         // 0: even k, 1: odd k
    int cq = lane128 << 2;       // c base (4 floats)
    int h = lane128 >> 4;        // head of this 16-lane group
    int sub = t & 15;

    float4 qrk4 = *(const float4*)(qrk_ws + nq * E + cq);
    float4 qv4 = *(const float4*)(qv_ws + nq * E + cq);
    float4 pq4 = *(const float4*)(pq_ws + nq * E + cq);

    const float4* relp = (const float4*)(rel + nq * (size_t)L * E);
    size_t nbase = ((size_t)n << 8);

    for (int kk = 0; kk < 128; kk++) {
        int k = (kk << 1) | rowsel;
        float4 r4 = relp[(k << 7) + lane128];
        const float4 kq4 = *(const float4*)(krq_ws + (nbase + k) * E + cq);
        const float4 kp4 = *(const float4*)(kv_ws + (nbase + k) * E + cq);
        const float4 pk4 = *(const float4*)(pk_ws + (nbase + k) * E + cq);
        float p;
        p = r4.x * (qrk4.x + kq4.x);
        p = fmaf(r4.y, (qrk4.y + kq4.y), p);
        p = fmaf(r4.z, (qrk4.z + kq4.z), p);
        p = fmaf(r4.w, (qrk4.w + kq4.w), p);
        p = fmaf(kp4.x, qv4.x, p);
        p = fmaf(kp4.y, qv4.y, p);
        p = fmaf(kp4.z, qv4.z, p);
        p = fmaf(kp4.w, qv4.w, p);
        p = fmaf(pk4.x, pq4.x, p);
        p = fmaf(pk4.y, pq4.y, p);
        p = fmaf(pk4.z, pq4.z, p);
        p = fmaf(pk4.w, pq4.w, p);
        // reduce 16 lanes -> 1 (same h, same k)
        p += __shfl_down(p, 8, 16);
        p += __shfl_down(p, 4, 16);
        p += __shfl_down(p, 2, 16);
        p += __shfl_down(p, 1, 16);
        if (sub == 0) {
            e_s[h][k] = p * RSQRT2 + (1.0f - mask[(n << 8) + k]) * (-1e9f);
        }
    }
    __syncthreads();

    // softmax over k, 8 groups of 32 threads
    {
        int hh = t >> 5;
        int lane = t & 31;
        float m = -INFINITY;
#pragma unroll
        for (int j = 0; j < 8; j++) m = fmaxf(m, e_s[hh][lane + (j << 5)]);
#pragma unroll
        for (int off = 16; off > 0; off >>= 1) m = fmaxf(m, __shfl_xor(m, off, 32));
        float s = 0.f;
#pragma unroll
        for (int j = 0; j < 8; j++) {
            int idx = lane + (j << 5);
            float ev = __expf(e_s[hh][idx] - m);
            e_s[hh][idx] = ev;
            s += ev;
        }
#pragma unroll
        for (int off = 16; off > 0; off >>= 1) s += __shfl_xor(s, off, 32);
        if (lane == 0) inv_s[hh] = 1.0f / s;
    }
    __syncthreads();

    // attn @ V : thread handles c1 = t, c2 = t+256
    {
        int c1 = t, c2 = t + 256;
        int h1 = t >> 6, h2 = (t >> 6) + 4;
        float acc1 = 0.f, acc2 = 0.f;
        const float* vb = vv_ws + nbase * E;
#pragma unroll 4
        for (int k = 0; k < L; k++) {
            const float* vr = vb + ((size_t)k << 9);
            acc1 = fmaf(e_s[h1][k], vr[c1], acc1);
            acc2 = fmaf(e_s[h2][k], vr[c2], acc2);
        }
        attn_ws[nq * E + c1] = acc1 * inv_s[h1];
        attn_ws[nq * E + c2] = acc2 * inv_s[h2];
    }
}

// ---------------- K3: out = attn @ Wout.T + bout ----------------
// block handles 4 rows of attn_ws; WoutT is [c][e]
__global__ __launch_bounds__(256) void k3_out(const float* __restrict__ attn_ws,
                                              const float* __restrict__ WoutT,
                                              const float* __restrict__ bout,
                                              float* __restrict__ out) {
    __shared__ float As[4 * E];
    int t = threadIdx.x;
    int r0 = blockIdx.x << 2;
    for (int j = t; j < 4 * E; j += 256) As[j] = attn_ws[(size_t)r0 * E + j];
    __syncthreads();
    int e1 = t, e2 = t + 256;
    float a00 = bout[e1], a01 = bout[e2];
    float a10 = a00, a11 = a01, a20 = a00, a21 = a01, a30 = a00, a31 = a01;
#pragma unroll 4
    for (int c = 0; c < E; c++) {
        float w1 = WoutT[((size_t)c << 9) + e1];
        float w2 = WoutT[((size_t)c << 9) + e2];
        a00 = fmaf(As[c], w1, a00);
        a01 = fmaf(As[c], w2, a01);
        a10 = fmaf(As[E + c], w1, a10);
        a11 = fmaf(As[E + c], w2, a11);
        a20 = fmaf(As[2 * E + c], w1, a20);
        a21 = fmaf(As[2 * E + c], w2, a21);
        a30 = fmaf(As[3 * E + c], w1, a30);
        a31 = fmaf(As[3 * E + c], w2, a31);
    }
    out[(size_t)(r0 + 0) * E + e1] = a00;
    out[(size_t)(r0 + 0) * E + e2] = a01;
    out[(size_t)(r0 + 1) * E + e1] = a10;
    out[(size_t)(r0 + 1) * E + e2] = a11;
    out[(size_t)(r0 + 2) * E + e1] = a20;
    out[(size_t)(r0 + 2) * E + e2] = a21;
    out[(size_t)(r0 + 3) * E + e1] = a30;
    out[(size_t)(r0 + 3) * E + e2] = a31;
}

extern "C" void kernel_launch(void* const* d_in, const int* in_sizes, int n_in,
                              void* d_out, int out_size, void* d_ws, size_t ws_size,
                              hipStream_t stream) {
    const float* values = (const float*)d_in[0];
    const float* keys = (const float*)d_in[1];
    const float* query = (const float*)d_in[2];
    const float* pos = (const float*)d_in[3];
    const float* rel = (const float*)d_in[4];
    const float* mask = (const float*)d_in[5];
    const float* Wv = (const float*)d_in[6];
    const float* Wk = (const float*)d_in[7];
    const float* Wq = (const float*)d_in[8];
    const float* Wpq = (const float*)d_in[9];
    const float* Wpk = (const float*)d_in[10];
    const float* Wrk = (const float*)d_in[11];
    const float* Wrq = (const float*)d_in[12];
    const float* Wout = (const float*)d_in[13];
    const float* bout = (const float*)d_in[14];
    float* out = (float*)d_out;

    float* ws = (float*)d_ws;
    const size_t SZ = (size_t)NL * E;  // 262144
    float* qv_ws = ws + 0 * SZ;
    float* kv_ws = ws + 1 * SZ;
    float* vv_ws = ws + 2 * SZ;
    float* pq_ws = ws + 3 * SZ;
    float* pk_ws = ws + 4 * SZ;
    float* qrk_ws = ws + 5 * SZ;
    float* krq_ws = ws + 6 * SZ;
    float* attn_ws = ws + 7 * SZ;
    float* WoutT = ws + 8 * SZ;

    k0_transpose<<<64, 256, 0, stream>>>(Wout, WoutT);
    k1_proj<<<NL, 256, 0, stream>>>(values, keys, query, pos, Wv, Wk, Wq, Wpq,
                                    Wpk, Wrk, Wrq, qv_ws, kv_ws, vv_ws, pq_ws,
                                    pk_ws, qrk_ws, krq_ws);
    k2_attn<<<NL, 256, 0, stream>>>(rel, mask, qv_ws, kv_ws, vv_ws, pq_ws,
                                    pk_ws, qrk_ws, krq_ws, attn_ws);
    k3_out<<<NL / 4, 256, 0, stream>>>(attn_ws, WoutT, bout, out);
}

// Round 2
// 517.943 us; speedup vs baseline: 1.2045x; 1.2045x over previous
//
#include <hip/hip_runtime.h>
#include <hip/hip_bf16.h>

#define NB 2
#define L 256
#define H 8
#define D 64
#define E 512
#define NL (NB * L)
#define RSQRT2 0.70710678118654752f

// ---------------- K0: transpose Wout [E][E] -> WoutT [c][e] ----------------
__global__ __launch_bounds__(256) void k0_transpose(const float* __restrict__ Wout,
                                                    float* __restrict__ WoutT) {
    __shared__ float tile[64][65];
    int t = threadIdx.x;
    int bi = blockIdx.x >> 3;   // e-tile
    int bj = blockIdx.x & 7;    // c-tile
    int tx = t & 63, ty = t >> 6;  // ty 0..3
#pragma unroll
    for (int m = 0; m < 16; m++) {
        int el = ty + (m << 2);
        tile[el][tx] = Wout[(size_t)(bi * 64 + el) * E + bj * 64 + tx];
    }
    __syncthreads();
#pragma unroll
    for (int m = 0; m < 16; m++) {
        int cl = ty + (m << 2);
        WoutT[(size_t)(bj * 64 + cl) * E + bi * 64 + tx] = tile[tx][cl];
    }
}

// ---------------- K1: per-(n,l) projections ----------------
__device__ __forceinline__ float dot64(const float* __restrict__ a,
                                       const float* __restrict__ w) {
    const float4* a4 = (const float4*)a;
    const float4* w4 = (const float4*)w;
    float acc = 0.f;
#pragma unroll
    for (int j = 0; j < 16; j++) {
        float4 x = a4[j], y = w4[j];
        acc = fmaf(x.x, y.x, acc);
        acc = fmaf(x.y, y.y, acc);
        acc = fmaf(x.z, y.z, acc);
        acc = fmaf(x.w, y.w, acc);
    }
    return acc;
}

__global__ __launch_bounds__(256) void k1_proj(
    const float* __restrict__ values, const float* __restrict__ keys,
    const float* __restrict__ query, const float* __restrict__ pos,
    const float* __restrict__ Wv, const float* __restrict__ Wk,
    const float* __restrict__ Wq, const float* __restrict__ Wpq,
    const float* __restrict__ Wpk, const float* __restrict__ Wrk,
    const float* __restrict__ Wrq,
    float* __restrict__ qv_ws, float* __restrict__ kv_ws,
    float* __restrict__ vv_ws, float* __restrict__ pq_ws,
    float* __restrict__ pk_ws, float* __restrict__ qrk_ws,
    float* __restrict__ krq_ws) {
    __shared__ float xq[E], xk[E], xv[E], xp[E];
    __shared__ float qs[E], ks[E];
    int t = threadIdx.x;
    int nl = blockIdx.x;
    size_t base = (size_t)nl * E;
    for (int j = t; j < E; j += 256) {
        xq[j] = query[base + j];
        xk[j] = keys[base + j];
        xv[j] = values[base + j];
        xp[j] = pos[base + j];
    }
    __syncthreads();
#pragma unroll
    for (int cc = 0; cc < 2; cc++) {
        int c = t + cc * 256;
        int h = c >> 6, i = c & 63;
        const float* xqh = xq + (h << 6);
        const float* xkh = xk + (h << 6);
        const float* xvh = xv + (h << 6);
        const float* xph = xp + (h << 6);
        float q_c = dot64(xqh, Wq + (i << 6));
        float k_c = dot64(xkh, Wk + (i << 6));
        float v_c = dot64(xvh, Wv + (i << 6));
        float pq_c = dot64(xph, Wpq + (i << 6));
        float pk_c = dot64(xph, Wpk + (i << 6));
        qv_ws[base + c] = q_c;
        kv_ws[base + c] = k_c;
        vv_ws[base + c] = v_c;
        pq_ws[base + c] = pq_c;
        pk_ws[base + c] = pk_c;
        qs[c] = q_c;
        ks[c] = k_c;
    }
    __syncthreads();
#pragma unroll
    for (int cc = 0; cc < 2; cc++) {
        int c = t + cc * 256;
        int h = c >> 6, d = c & 63;
        float aq = 0.f, ak = 0.f;
        const float* qh = qs + (h << 6);
        const float* kh = ks + (h << 6);
#pragma unroll 8
        for (int i = 0; i < 64; i++) {
            aq = fmaf(qh[i], Wrk[(i << 6) + d], aq);
            ak = fmaf(kh[i], Wrq[(i << 6) + d], ak);
        }
        qrk_ws[base + c] = aq;
        krq_ws[base + c] = ak;
    }
}

// ---------------- K2a: energy, grid split over k ----------------
// block = (nq, kc); 4096 blocks; each block handles 32 k values.
__global__ __launch_bounds__(256) void k2a_energy(
    const float* __restrict__ rel, const float* __restrict__ mask,
    const float* __restrict__ qv_ws, const float* __restrict__ kv_ws,
    const float* __restrict__ pq_ws, const float* __restrict__ pk_ws,
    const float* __restrict__ qrk_ws, const float* __restrict__ krq_ws,
    float* __restrict__ e_ws) {
    int t = threadIdx.x;
    int b = blockIdx.x;
    int kc = b & 7;
    int nq = b >> 3;
    int n = nq >> 8;

    int lane128 = t & 127;
    int rowsel = t >> 7;         // 0: even k, 1: odd k
    int cq = lane128 << 2;       // c base (4 floats)
    int h = lane128 >> 4;
    int sub = t & 15;

    float4 qrk4 = *(const float4*)(qrk_ws + (size_t)nq * E + cq);
    float4 qv4 = *(const float4*)(qv_ws + (size_t)nq * E + cq);
    float4 pq4 = *(const float4*)(pq_ws + (size_t)nq * E + cq);

    const float* relb = rel + (size_t)nq * L * E;
    size_t nbase = ((size_t)n << 8);
    float* eb = e_ws + (size_t)nq * (H * L);

#pragma unroll 4
    for (int kk = 0; kk < 16; kk++) {
        int k = (kc << 5) + (kk << 1) + rowsel;
        float4 r4 = *(const float4*)(relb + ((size_t)k << 9) + cq);
        float4 kq4 = *(const float4*)(krq_ws + (nbase + k) * E + cq);
        float4 kp4 = *(const float4*)(kv_ws + (nbase + k) * E + cq);
        float4 pk4 = *(const float4*)(pk_ws + (nbase + k) * E + cq);
        float p;
        p = r4.x * (qrk4.x + kq4.x);
        p = fmaf(r4.y, (qrk4.y + kq4.y), p);
        p = fmaf(r4.z, (qrk4.z + kq4.z), p);
        p = fmaf(r4.w, (qrk4.w + kq4.w), p);
        p = fmaf(kp4.x, qv4.x, p);
        p = fmaf(kp4.y, qv4.y, p);
        p = fmaf(kp4.z, qv4.z, p);
        p = fmaf(kp4.w, qv4.w, p);
        p = fmaf(pk4.x, pq4.x, p);
        p = fmaf(pk4.y, pq4.y, p);
        p = fmaf(pk4.z, pq4.z, p);
        p = fmaf(pk4.w, pq4.w, p);
        p += __shfl_down(p, 8, 16);
        p += __shfl_down(p, 4, 16);
        p += __shfl_down(p, 2, 16);
        p += __shfl_down(p, 1, 16);
        if (sub == 0) {
            eb[(h << 8) + k] = p * RSQRT2 + (1.0f - mask[(n << 8) + k]) * (-1e9f);
        }
    }
}

// ---------------- K2b: softmax + attn @ V, one block per (n,q) ----------------
__global__ __launch_bounds__(512) void k2b_soft_av(
    const float* __restrict__ e_ws, const float* __restrict__ vv_ws,
    float* __restrict__ attn_ws) {
    __shared__ float e_s[H * L];
    __shared__ float inv_s[H];
    int t = threadIdx.x;
    int nq = blockIdx.x;
    int n = nq >> 8;

    ((float4*)e_s)[t] = ((const float4*)(e_ws + (size_t)nq * (H * L)))[t];
    __syncthreads();

    // softmax: one 64-lane wave per head
    {
        int hh = t >> 6;
        int lane = t & 63;
        float* eh = e_s + (hh << 8);
        float m = -INFINITY;
#pragma unroll
        for (int j = 0; j < 4; j++) m = fmaxf(m, eh[lane + (j << 6)]);
#pragma unroll
        for (int off = 32; off > 0; off >>= 1) m = fmaxf(m, __shfl_xor(m, off, 64));
        float s = 0.f;
#pragma unroll
        for (int j = 0; j < 4; j++) {
            int idx = lane + (j << 6);
            float ev = __expf(eh[idx] - m);
            eh[idx] = ev;
            s += ev;
        }
#pragma unroll
        for (int off = 32; off > 0; off >>= 1) s += __shfl_xor(s, off, 64);
        if (lane == 0) inv_s[hh] = 1.0f / s;
    }
    __syncthreads();

    // attn @ V : thread t owns channel c = t
    {
        int c = t;
        int h1 = t >> 6;
        const float* eh = e_s + (h1 << 8);
        float acc = 0.f;
        const float* vb = vv_ws + (((size_t)n << 8) * E);
#pragma unroll 8
        for (int k = 0; k < L; k++) {
            acc = fmaf(eh[k], vb[((size_t)k << 9) + c], acc);
        }
        attn_ws[(size_t)nq * E + c] = acc * inv_s[h1];
    }
}

// ---------------- K3: out = attn @ Wout.T + bout (1 row / block) ----------------
__global__ __launch_bounds__(512) void k3_out(const float* __restrict__ attn_ws,
                                              const float* __restrict__ WoutT,
                                              const float* __restrict__ bout,
                                              float* __restrict__ out) {
    __shared__ float As[E];
    int t = threadIdx.x;
    int r = blockIdx.x;
    As[t] = attn_ws[(size_t)r * E + t];
    __syncthreads();
    float acc = bout[t];
#pragma unroll 8
    for (int c = 0; c < E; c++) {
        acc = fmaf(As[c], WoutT[((size_t)c << 9) + t], acc);
    }
    out[(size_t)r * E + t] = acc;
}

extern "C" void kernel_launch(void* const* d_in, const int* in_sizes, int n_in,
                              void* d_out, int out_size, void* d_ws, size_t ws_size,
                              hipStream_t stream) {
    const float* values = (const float*)d_in[0];
    const float* keys = (const float*)d_in[1];
    const float* query = (const float*)d_in[2];
    const float* pos = (const float*)d_in[3];
    const float* rel = (const float*)d_in[4];
    const float* mask = (const float*)d_in[5];
    const float* Wv = (const float*)d_in[6];
    const float* Wk = (const float*)d_in[7];
    const float* Wq = (const float*)d_in[8];
    const float* Wpq = (const float*)d_in[9];
    const float* Wpk = (const float*)d_in[10];
    const float* Wrk = (const float*)d_in[11];
    const float* Wrq = (const float*)d_in[12];
    const float* Wout = (const float*)d_in[13];
    const float* bout = (const float*)d_in[14];
    float* out = (float*)d_out;

    float* ws = (float*)d_ws;
    const size_t SZ = (size_t)NL * E;  // 262144 floats = 1 MB
    float* qv_ws = ws + 0 * SZ;
    float* kv_ws = ws + 1 * SZ;
    float* vv_ws = ws + 2 * SZ;
    float* pq_ws = ws + 3 * SZ;
    float* pk_ws = ws + 4 * SZ;
    float* qrk_ws = ws + 5 * SZ;
    float* krq_ws = ws + 6 * SZ;
    float* attn_ws = ws + 7 * SZ;
    float* WoutT = ws + 8 * SZ;
    float* e_ws = ws + 9 * SZ;  // NL * H * L floats = 4 MB

    k0_transpose<<<64, 256, 0, stream>>>(Wout, WoutT);
    k1_proj<<<NL, 256, 0, stream>>>(values, keys, query, pos, Wv, Wk, Wq, Wpq,
                                    Wpk, Wrk, Wrq, qv_ws, kv_ws, vv_ws, pq_ws,
                                    pk_ws, qrk_ws, krq_ws);
    k2a_energy<<<NL * 8, 256, 0, stream>>>(rel, mask, qv_ws, kv_ws, pq_ws,
                                           pk_ws, qrk_ws, krq_ws, e_ws);
    k2b_soft_av<<<NL, 512, 0, stream>>>(e_ws, vv_ws, attn_ws);
    k3_out<<<NL, 512, 0, stream>>>(attn_ws, WoutT, bout, out);
}

// Round 3
// 491.921 us; speedup vs baseline: 1.2683x; 1.0529x over previous
//
#include <hip/hip_runtime.h>
#include <hip/hip_bf16.h>

#define NB 2
#define L 256
#define H 8
#define D 64
#define E 512
#define NL (NB * L)
#define RSQRT2 0.70710678118654752f

// ---------------- K0: transpose Wout [E][E] -> WoutT [c][e] ----------------
__global__ __launch_bounds__(256) void k0_transpose(const float* __restrict__ Wout,
                                                    float* __restrict__ WoutT) {
    __shared__ float tile[64][65];
    int t = threadIdx.x;
    int bi = blockIdx.x >> 3;   // e-tile
    int bj = blockIdx.x & 7;    // c-tile
    int tx = t & 63, ty = t >> 6;  // ty 0..3
#pragma unroll
    for (int m = 0; m < 16; m++) {
        int el = ty + (m << 2);
        tile[el][tx] = Wout[(size_t)(bi * 64 + el) * E + bj * 64 + tx];
    }
    __syncthreads();
#pragma unroll
    for (int m = 0; m < 16; m++) {
        int cl = ty + (m << 2);
        WoutT[(size_t)(bj * 64 + cl) * E + bi * 64 + tx] = tile[tx][cl];
    }
}

// ---------------- K1: per-(n,l) projections ----------------
__device__ __forceinline__ float dot64(const float* __restrict__ a,
                                       const float* __restrict__ w) {
    const float4* a4 = (const float4*)a;
    const float4* w4 = (const float4*)w;
    float acc = 0.f;
#pragma unroll
    for (int j = 0; j < 16; j++) {
        float4 x = a4[j], y = w4[j];
        acc = fmaf(x.x, y.x, acc);
        acc = fmaf(x.y, y.y, acc);
        acc = fmaf(x.z, y.z, acc);
        acc = fmaf(x.w, y.w, acc);
    }
    return acc;
}

__global__ __launch_bounds__(256) void k1_proj(
    const float* __restrict__ values, const float* __restrict__ keys,
    const float* __restrict__ query, const float* __restrict__ pos,
    const float* __restrict__ Wv, const float* __restrict__ Wk,
    const float* __restrict__ Wq, const float* __restrict__ Wpq,
    const float* __restrict__ Wpk, const float* __restrict__ Wrk,
    const float* __restrict__ Wrq,
    float* __restrict__ qv_ws, float* __restrict__ kv_ws,
    float* __restrict__ vv_ws, float* __restrict__ pq_ws,
    float* __restrict__ pk_ws, float* __restrict__ qrk_ws,
    float* __restrict__ krq_ws) {
    __shared__ float xq[E], xk[E], xv[E], xp[E];
    __shared__ float qs[E], ks[E];
    int t = threadIdx.x;
    int nl = blockIdx.x;
    size_t base = (size_t)nl * E;
    for (int j = t; j < E; j += 256) {
        xq[j] = query[base + j];
        xk[j] = keys[base + j];
        xv[j] = values[base + j];
        xp[j] = pos[base + j];
    }
    __syncthreads();
#pragma unroll
    for (int cc = 0; cc < 2; cc++) {
        int c = t + cc * 256;
        int h = c >> 6, i = c & 63;
        const float* xqh = xq + (h << 6);
        const float* xkh = xk + (h << 6);
        const float* xvh = xv + (h << 6);
        const float* xph = xp + (h << 6);
        float q_c = dot64(xqh, Wq + (i << 6));
        float k_c = dot64(xkh, Wk + (i << 6));
        float v_c = dot64(xvh, Wv + (i << 6));
        float pq_c = dot64(xph, Wpq + (i << 6));
        float pk_c = dot64(xph, Wpk + (i << 6));
        qv_ws[base + c] = q_c;
        kv_ws[base + c] = k_c;
        vv_ws[base + c] = v_c;
        pq_ws[base + c] = pq_c;
        pk_ws[base + c] = pk_c;
        qs[c] = q_c;
        ks[c] = k_c;
    }
    __syncthreads();
#pragma unroll
    for (int cc = 0; cc < 2; cc++) {
        int c = t + cc * 256;
        int h = c >> 6, d = c & 63;
        float aq = 0.f, ak = 0.f;
        const float* qh = qs + (h << 6);
        const float* kh = ks + (h << 6);
#pragma unroll 8
        for (int i = 0; i < 64; i++) {
            aq = fmaf(qh[i], Wrk[(i << 6) + d], aq);
            ak = fmaf(kh[i], Wrq[(i << 6) + d], ak);
        }
        qrk_ws[base + c] = aq;
        krq_ws[base + c] = ak;
    }
}

// ---------------- K2a: energy; block = (n, qtile16, kchunk16) ----------------
// 512 blocks x 256 threads. k-side vectors live in registers for the whole block.
__global__ __launch_bounds__(256, 2) void k2a_energy(
    const float* __restrict__ rel, const float* __restrict__ mask,
    const float* __restrict__ qv_ws, const float* __restrict__ kv_ws,
    const float* __restrict__ pq_ws, const float* __restrict__ pk_ws,
    const float* __restrict__ qrk_ws, const float* __restrict__ krq_ws,
    float* __restrict__ e_ws) {
    int t = threadIdx.x;
    int b = blockIdx.x;
    int kc = b & 15;            // 16 k-chunks of 16 k
    int qt = (b >> 4) & 15;     // 16 q-tiles of 16 q
    int n = b >> 8;

    int lane128 = t & 127;
    int rowsel = t >> 7;        // k parity within the chunk
    int cq = lane128 << 2;      // channel base (4 floats)
    int h = lane128 >> 4;
    int sub = t & 15;
    size_t nbase = (size_t)n << 8;
    int kb = kc << 4;

    // preload k-side for my parity: 8 k values
    float4 kq[8], kp[8], pk[8];
    float mk[8];
#pragma unroll
    for (int jj = 0; jj < 8; jj++) {
        int k = kb + (jj << 1) + rowsel;
        kq[jj] = *(const float4*)(krq_ws + (nbase + k) * E + cq);
        kp[jj] = *(const float4*)(kv_ws + (nbase + k) * E + cq);
        pk[jj] = *(const float4*)(pk_ws + (nbase + k) * E + cq);
        mk[jj] = (1.0f - mask[nbase + k]) * (-1e9f);
    }

    for (int qi = 0; qi < 16; qi++) {
        int q = (qt << 4) + qi;
        size_t nq = nbase + q;
        float4 qrk4 = *(const float4*)(qrk_ws + nq * E + cq);
        float4 qv4 = *(const float4*)(qv_ws + nq * E + cq);
        float4 pq4 = *(const float4*)(pq_ws + nq * E + cq);
        const float* relb = rel + nq * (size_t)(L * E);
        float4 r[8];
#pragma unroll
        for (int jj = 0; jj < 8; jj++) {
            int k = kb + (jj << 1) + rowsel;
            r[jj] = *(const float4*)(relb + ((size_t)k << 9) + cq);
        }
        float* eb = e_ws + nq * (H * L);
#pragma unroll
        for (int jj = 0; jj < 8; jj++) {
            float p;
            p = r[jj].x * (qrk4.x + kq[jj].x);
            p = fmaf(r[jj].y, (qrk4.y + kq[jj].y), p);
            p = fmaf(r[jj].z, (qrk4.z + kq[jj].z), p);
            p = fmaf(r[jj].w, (qrk4.w + kq[jj].w), p);
            p = fmaf(kp[jj].x, qv4.x, p);
            p = fmaf(kp[jj].y, qv4.y, p);
            p = fmaf(kp[jj].z, qv4.z, p);
            p = fmaf(kp[jj].w, qv4.w, p);
            p = fmaf(pk[jj].x, pq4.x, p);
            p = fmaf(pk[jj].y, pq4.y, p);
            p = fmaf(pk[jj].z, pq4.z, p);
            p = fmaf(pk[jj].w, pq4.w, p);
            p += __shfl_down(p, 8, 16);
            p += __shfl_down(p, 4, 16);
            p += __shfl_down(p, 2, 16);
            p += __shfl_down(p, 1, 16);
            if (sub == 0) {
                int k = kb + (jj << 1) + rowsel;
                eb[(h << 8) + k] = p * RSQRT2 + mk[jj];
            }
        }
    }
}

// ---------------- K2b: softmax + attn @ V, one block per (n,q) ----------------
__global__ __launch_bounds__(512) void k2b_soft_av(
    const float* __restrict__ e_ws, const float* __restrict__ vv_ws,
    float* __restrict__ attn_ws) {
    __shared__ float e_s[H * L];
    __shared__ float inv_s[H];
    int t = threadIdx.x;
    int nq = blockIdx.x;
    int n = nq >> 8;

    ((float4*)e_s)[t] = ((const float4*)(e_ws + (size_t)nq * (H * L)))[t];
    __syncthreads();

    // softmax: one 64-lane wave per head
    {
        int hh = t >> 6;
        int lane = t & 63;
        float* eh = e_s + (hh << 8);
        float m = -INFINITY;
#pragma unroll
        for (int j = 0; j < 4; j++) m = fmaxf(m, eh[lane + (j << 6)]);
#pragma unroll
        for (int off = 32; off > 0; off >>= 1) m = fmaxf(m, __shfl_xor(m, off, 64));
        float s = 0.f;
#pragma unroll
        for (int j = 0; j < 4; j++) {
            int idx = lane + (j << 6);
            float ev = __expf(eh[idx] - m);
            eh[idx] = ev;
            s += ev;
        }
#pragma unroll
        for (int off = 32; off > 0; off >>= 1) s += __shfl_xor(s, off, 64);
        if (lane == 0) inv_s[hh] = 1.0f / s;
    }
    __syncthreads();

    // attn @ V : thread t owns channel c = t
    {
        int c = t;
        int h1 = t >> 6;
        const float* eh = e_s + (h1 << 8);
        float acc = 0.f;
        const float* vb = vv_ws + (((size_t)n << 8) * E);
#pragma unroll 8
        for (int k = 0; k < L; k++) {
            acc = fmaf(eh[k], vb[((size_t)k << 9) + c], acc);
        }
        attn_ws[(size_t)nq * E + c] = acc * inv_s[h1];
    }
}

// ---------------- K3: out = attn @ Wout.T + bout (4 rows / block) ----------------
__global__ __launch_bounds__(512) void k3_out(const float* __restrict__ attn_ws,
                                              const float* __restrict__ WoutT,
                                              const float* __restrict__ bout,
                                              float* __restrict__ out) {
    __shared__ float As[4 * E];
    int t = threadIdx.x;
    int r0 = blockIdx.x << 2;
    for (int j = t; j < 4 * E; j += 512) As[j] = attn_ws[(size_t)r0 * E + j];
    __syncthreads();
    float b0 = bout[t];
    float a0 = b0, a1 = b0, a2 = b0, a3 = b0;
#pragma unroll 8
    for (int c = 0; c < E; c++) {
        float w = WoutT[((size_t)c << 9) + t];
        a0 = fmaf(As[c], w, a0);
        a1 = fmaf(As[E + c], w, a1);
        a2 = fmaf(As[2 * E + c], w, a2);
        a3 = fmaf(As[3 * E + c], w, a3);
    }
    out[(size_t)(r0 + 0) * E + t] = a0;
    out[(size_t)(r0 + 1) * E + t] = a1;
    out[(size_t)(r0 + 2) * E + t] = a2;
    out[(size_t)(r0 + 3) * E + t] = a3;
}

extern "C" void kernel_launch(void* const* d_in, const int* in_sizes, int n_in,
                              void* d_out, int out_size, void* d_ws, size_t ws_size,
                              hipStream_t stream) {
    const float* values = (const float*)d_in[0];
    const float* keys = (const float*)d_in[1];
    const float* query = (const float*)d_in[2];
    const float* pos = (const float*)d_in[3];
    const float* rel = (const float*)d_in[4];
    const float* mask = (const float*)d_in[5];
    const float* Wv = (const float*)d_in[6];
    const float* Wk = (const float*)d_in[7];
    const float* Wq = (const float*)d_in[8];
    const float* Wpq = (const float*)d_in[9];
    const float* Wpk = (const float*)d_in[10];
    const float* Wrk = (const float*)d_in[11];
    const float* Wrq = (const float*)d_in[12];
    const float* Wout = (const float*)d_in[13];
    const float* bout = (const float*)d_in[14];
    float* out = (float*)d_out;

    float* ws = (float*)d_ws;
    const size_t SZ = (size_t)NL * E;  // 262144 floats = 1 MB
    float* qv_ws = ws + 0 * SZ;
    float* kv_ws = ws + 1 * SZ;
    float* vv_ws = ws + 2 * SZ;
    float* pq_ws = ws + 3 * SZ;
    float* pk_ws = ws + 4 * SZ;
    float* qrk_ws = ws + 5 * SZ;
    float* krq_ws = ws + 6 * SZ;
    float* attn_ws = ws + 7 * SZ;
    float* WoutT = ws + 8 * SZ;
    float* e_ws = ws + 9 * SZ;  // NL * H * L floats = 4 MB

    k0_transpose<<<64, 256, 0, stream>>>(Wout, WoutT);
    k1_proj<<<NL, 256, 0, stream>>>(values, keys, query, pos, Wv, Wk, Wq, Wpq,
                                    Wpk, Wrk, Wrq, qv_ws, kv_ws, vv_ws, pq_ws,
                                    pk_ws, qrk_ws, krq_ws);
    k2a_energy<<<512, 256, 0, stream>>>(rel, mask, qv_ws, kv_ws, pq_ws,
                                        pk_ws, qrk_ws, krq_ws, e_ws);
    k2b_soft_av<<<NL, 512, 0, stream>>>(e_ws, vv_ws, attn_ws);
    k3_out<<<NL / 4, 512, 0, stream>>>(attn_ws, WoutT, bout, out);
}